// Round 1
// baseline (923.700 us; speedup 1.0000x reference)
//
#include <hip/hip_runtime.h>

// GAT 2-layer forward on MI355X.
// Round 0: correctness-first full implementation.
//   - Device-built dst-CSR (hist + scan + fill) reused by both layers.
//   - Two-pass segment softmax per (node, head), storing exp(e-m); the 1/(s+eps)
//     normalization is folded into the aggregation epilogue.
//   - Aggregation: thread = (node, float4-of-channels) -> coalesced 128/160B row
//     gathers of h[src] per edge.
//   - All fp32 (threshold 4.69e-3; fp32 gives ~1e-5).

#define DEVFN __device__ __forceinline__

// ---------------- edge dtype detection (int64 vs int32) ----------------
__global__ void detect_kernel(const int* eg32, int E, int* flag) {
  __shared__ int any;
  if (threadIdx.x == 0) any = 0;
  __syncthreads();
  for (int k = threadIdx.x; k < 2048 && k < E; k += 256) {
    if (eg32[2 * k + 1] != 0) atomicOr(&any, 1);
  }
  __syncthreads();
  if (threadIdx.x == 0) flag[0] = any ? 0 : 1;  // 1 => int64
}

DEVFN void read_edge(const long long* eg64, const int* eg32, int is64, int E,
                     int N, int i, int& s, int& d) {
  if (i >= E) { s = d = i - E; return; }  // self-loop
  if (is64) { s = (int)eg64[i]; d = (int)eg64[E + i]; }
  else      { s = eg32[i];      d = eg32[E + i]; }
}

// ---------------- CSR build ----------------
__global__ void zero_int(int* p, int n) {
  int i = blockIdx.x * 256 + threadIdx.x;
  if (i < n) p[i] = 0;
}

__global__ void hist_kernel(const long long* eg64, const int* eg32, const int* flag,
                            int E, int N, int* cnt) {
  int i = blockIdx.x * 256 + threadIdx.x;
  int EN = E + N;
  if (i >= EN) return;
  int is64 = flag[0];
  int s, d;
  read_edge(eg64, eg32, is64, E, N, i, s, d);
  atomicAdd(&cnt[d], 1);
}

__global__ void scan_blocks(const int* __restrict__ cnt, int* __restrict__ rp,
                            int* __restrict__ bsum, int n) {
  __shared__ int buf[2][1024];
  int t = threadIdx.x;
  int gid = blockIdx.x * 1024 + t;
  int v = (gid < n) ? cnt[gid] : 0;
  buf[0][t] = v;
  __syncthreads();
  int pin = 0;
  for (int offd = 1; offd < 1024; offd <<= 1) {
    int nv = buf[pin][t];
    if (t >= offd) nv += buf[pin][t - offd];
    buf[1 - pin][t] = nv;
    pin = 1 - pin;
    __syncthreads();
  }
  int inc = buf[pin][t];
  if (gid < n) rp[gid] = inc - v;  // exclusive within block
  if (t == 1023) bsum[blockIdx.x] = inc;
}

__global__ void scan_sums(const int* bsum, int* boff, int nb) {
  if (blockIdx.x == 0 && threadIdx.x == 0) {
    int r = 0;
    for (int i = 0; i < nb; i++) { boff[i] = r; r += bsum[i]; }
  }
}

__global__ void scan_add(int* rp, int* cursor, const int* boff, int n, int total) {
  int i = blockIdx.x * 1024 + threadIdx.x;
  if (i < n) {
    int v = rp[i] + boff[blockIdx.x];
    rp[i] = v;
    cursor[i] = v;
  }
  if (i == 0) rp[n] = total;
}

__global__ void fill_kernel(const long long* eg64, const int* eg32, const int* flag,
                            int E, int N, int* cursor, int* csr_src) {
  int i = blockIdx.x * 256 + threadIdx.x;
  int EN = E + N;
  if (i >= EN) return;
  int is64 = flag[0];
  int s, d;
  read_edge(eg64, eg32, is64, E, N, i, s, d);
  int pos = atomicAdd(&cursor[d], 1);
  csr_src[pos] = s;
}

// ---------------- dense GEMMs ----------------
// h1[N,32] = X[N,128] @ W1[128,32]; thread = (row, 4 consecutive out channels)
__global__ __launch_bounds__(256) void gemm1_kernel(const float* __restrict__ X,
                                                    const float* __restrict__ W,
                                                    float* __restrict__ h1, int N) {
  __shared__ float Wl[128 * 32];
  int t = threadIdx.x;
  for (int i = t; i < 128 * 32 / 4; i += 256)
    ((float4*)Wl)[i] = ((const float4*)W)[i];
  __syncthreads();
  int idx = blockIdx.x * 256 + t;  // over N*8
  if (idx >= N * 8) return;
  int n = idx >> 3, cq = idx & 7;
  const float4* X4 = (const float4*)(X + (size_t)n * 128);
  float4 acc = make_float4(0.f, 0.f, 0.f, 0.f);
#pragma unroll
  for (int k4 = 0; k4 < 32; k4++) {
    float4 x = X4[k4];
    const float4* wr = (const float4*)(Wl + (k4 * 4) * 32 + cq * 4);
    float4 w0 = wr[0], w1 = wr[8], w2 = wr[16], w3 = wr[24];
    acc.x = fmaf(x.x, w0.x, acc.x); acc.y = fmaf(x.x, w0.y, acc.y);
    acc.z = fmaf(x.x, w0.z, acc.z); acc.w = fmaf(x.x, w0.w, acc.w);
    acc.x = fmaf(x.y, w1.x, acc.x); acc.y = fmaf(x.y, w1.y, acc.y);
    acc.z = fmaf(x.y, w1.z, acc.z); acc.w = fmaf(x.y, w1.w, acc.w);
    acc.x = fmaf(x.z, w2.x, acc.x); acc.y = fmaf(x.z, w2.y, acc.y);
    acc.z = fmaf(x.z, w2.z, acc.z); acc.w = fmaf(x.z, w2.w, acc.w);
    acc.x = fmaf(x.w, w3.x, acc.x); acc.y = fmaf(x.w, w3.y, acc.y);
    acc.z = fmaf(x.w, w3.z, acc.z); acc.w = fmaf(x.w, w3.w, acc.w);
  }
  ((float4*)h1)[idx] = acc;
}

// h2[N,40] = x1[N,32] @ W2[32,40]; thread = (row, 4 consecutive out channels)
__global__ __launch_bounds__(256) void gemm2_kernel(const float* __restrict__ X,
                                                    const float* __restrict__ W,
                                                    float* __restrict__ h2, int N) {
  __shared__ float Wl[32 * 40];
  int t = threadIdx.x;
  for (int i = t; i < 32 * 40 / 4; i += 256)
    ((float4*)Wl)[i] = ((const float4*)W)[i];
  __syncthreads();
  int idx = blockIdx.x * 256 + t;  // over N*10
  if (idx >= N * 10) return;
  int n = idx / 10, cq = idx % 10;
  const float4* X4 = (const float4*)(X + (size_t)n * 32);
  float4 acc = make_float4(0.f, 0.f, 0.f, 0.f);
#pragma unroll
  for (int k4 = 0; k4 < 8; k4++) {
    float4 x = X4[k4];
    const float4* wr = (const float4*)(Wl + (k4 * 4) * 40 + cq * 4);
    float4 w0 = wr[0], w1 = wr[10], w2 = wr[20], w3 = wr[30];
    acc.x = fmaf(x.x, w0.x, acc.x); acc.y = fmaf(x.x, w0.y, acc.y);
    acc.z = fmaf(x.x, w0.z, acc.z); acc.w = fmaf(x.x, w0.w, acc.w);
    acc.x = fmaf(x.y, w1.x, acc.x); acc.y = fmaf(x.y, w1.y, acc.y);
    acc.z = fmaf(x.y, w1.z, acc.z); acc.w = fmaf(x.y, w1.w, acc.w);
    acc.x = fmaf(x.z, w2.x, acc.x); acc.y = fmaf(x.z, w2.y, acc.y);
    acc.z = fmaf(x.z, w2.z, acc.z); acc.w = fmaf(x.z, w2.w, acc.w);
    acc.x = fmaf(x.w, w3.x, acc.x); acc.y = fmaf(x.w, w3.y, acc.y);
    acc.z = fmaf(x.w, w3.z, acc.z); acc.w = fmaf(x.w, w3.w, acc.w);
  }
  ((float4*)h2)[idx] = acc;
}

// ---------------- attention scalar projections ----------------
template <int H, int C>
__global__ __launch_bounds__(256) void attn_kernel(const float* __restrict__ h,
                                                   const float* __restrict__ att_s,
                                                   const float* __restrict__ att_d,
                                                   float* __restrict__ as,
                                                   float* __restrict__ ad, int N) {
  int n = blockIdx.x * 256 + threadIdx.x;
  if (n >= N) return;
  const float* hr = h + (size_t)n * (H * C);
#pragma unroll
  for (int hh = 0; hh < H; hh++) {
    float ss = 0.f, sd = 0.f;
#pragma unroll
    for (int c = 0; c < C; c++) {
      float v = hr[hh * C + c];
      ss = fmaf(v, att_s[hh * C + c], ss);
      sd = fmaf(v, att_d[hh * C + c], sd);
    }
    as[n * H + hh] = ss;
    ad[n * H + hh] = sd;
  }
}

// ---------------- segment softmax (two-pass, stores exp(e-m)) ----------------
template <int H>
__global__ __launch_bounds__(256) void softmax_kernel(const int* __restrict__ rp,
                                                      const int* __restrict__ csr,
                                                      const float* __restrict__ as,
                                                      const float* __restrict__ ad,
                                                      float* __restrict__ alpha,
                                                      float* __restrict__ ssum, int N) {
  int t = blockIdx.x * 256 + threadIdx.x;
  if (t >= N * H) return;
  int n = t / H, h = t % H;
  int p0 = rp[n], p1 = rp[n + 1];
  float adv = ad[n * H + h];
  float m = -1e30f;
  for (int p = p0; p < p1; p++) {
    int s = csr[p];
    float e = as[s * H + h] + adv;
    e = e > 0.f ? e : 0.2f * e;
    m = fmaxf(m, e);
  }
  float sum = 0.f;
  for (int p = p0; p < p1; p++) {
    int s = csr[p];
    float e = as[s * H + h] + adv;
    e = e > 0.f ? e : 0.2f * e;
    float ex = expf(e - m);
    sum += ex;
    alpha[p * H + h] = ex;
  }
  ssum[n * H + h] = sum;
}

// ---------------- aggregation: thread = (node, float4 of channels) ----------------
template <int H, int C, bool RELU>
__global__ __launch_bounds__(256) void agg_kernel(const int* __restrict__ rp,
                                                  const int* __restrict__ csr,
                                                  const float* __restrict__ alpha,
                                                  const float* __restrict__ ssum,
                                                  const float* __restrict__ hfeat,
                                                  const float* __restrict__ bias,
                                                  float* __restrict__ outp, int N) {
  constexpr int HC = H * C;
  constexpr int QV = HC / 4;
  int idx = blockIdx.x * 256 + threadIdx.x;  // over N*QV
  if (idx >= N * QV) return;
  int n = idx / QV, cq = idx % QV;
  int h = (cq * 4) / C;
  int p0 = rp[n], p1 = rp[n + 1];
  const float4* hf4 = (const float4*)hfeat;
  float4 acc = make_float4(0.f, 0.f, 0.f, 0.f);
  for (int p = p0; p < p1; p++) {
    int s = csr[p];
    float a = alpha[p * H + h];
    float4 v = hf4[(size_t)s * QV + cq];
    acc.x = fmaf(a, v.x, acc.x);
    acc.y = fmaf(a, v.y, acc.y);
    acc.z = fmaf(a, v.z, acc.z);
    acc.w = fmaf(a, v.w, acc.w);
  }
  float inv = 1.0f / (ssum[n * H + h] + 1e-16f);
  float4 b = ((const float4*)bias)[cq];
  float4 r;
  r.x = acc.x * inv + b.x;
  r.y = acc.y * inv + b.y;
  r.z = acc.z * inv + b.z;
  r.w = acc.w * inv + b.w;
  if (RELU) {
    r.x = fmaxf(r.x, 0.f); r.y = fmaxf(r.y, 0.f);
    r.z = fmaxf(r.z, 0.f); r.w = fmaxf(r.w, 0.f);
  }
  ((float4*)outp)[idx] = r;
}

// ---------------- host launcher ----------------
extern "C" void kernel_launch(void* const* d_in, const int* in_sizes, int n_in,
                              void* d_out, int out_size, void* d_ws, size_t ws_size,
                              hipStream_t stream) {
  const float* X    = (const float*)d_in[0];
  const long long* eg64 = (const long long*)d_in[1];
  const int* eg32   = (const int*)d_in[1];
  const float* W1   = (const float*)d_in[3];
  const float* as1w = (const float*)d_in[4];
  const float* ad1w = (const float*)d_in[5];
  const float* b1   = (const float*)d_in[6];
  const float* W2   = (const float*)d_in[7];
  const float* as2w = (const float*)d_in[8];
  const float* ad2w = (const float*)d_in[9];
  const float* b2   = (const float*)d_in[10];
  float* out = (float*)d_out;

  const int N  = in_sizes[0] / 128;
  const int E  = in_sizes[1] / 2;
  const int EN = E + N;

  char* wbase = (char*)d_ws;
  size_t off = 0;
  auto alloc = [&](size_t bytes) -> void* {
    void* p = wbase + off;
    off += (bytes + 255) & ~(size_t)255;
    return p;
  };

  float* h1  = (float*)alloc((size_t)N * 32 * 4);
  float* x1  = (float*)alloc((size_t)N * 32 * 4);
  float* h2  = (float*)alloc((size_t)N * 40 * 4);
  float* as1 = (float*)alloc((size_t)N * 2 * 4);
  float* ad1 = (float*)alloc((size_t)N * 2 * 4);
  float* s1  = (float*)alloc((size_t)N * 2 * 4);
  float* as2 = (float*)alloc((size_t)N * 4);
  float* ad2 = (float*)alloc((size_t)N * 4);
  float* s2  = (float*)alloc((size_t)N * 4);
  int* cnt    = (int*)alloc((size_t)N * 4);
  int* rp     = (int*)alloc((size_t)(N + 1) * 4);
  int* cursor = (int*)alloc((size_t)N * 4);
  int* bsum   = (int*)alloc(1024 * 4);
  int* boff   = (int*)alloc(1024 * 4);
  int* flag   = (int*)alloc(256);
  int* csr    = (int*)alloc((size_t)EN * 4);
  float* al1  = (float*)alloc((size_t)EN * 2 * 4);
  float* al2  = (float*)alloc((size_t)EN * 4);
  (void)ws_size; (void)n_in; (void)out_size;

  const int nb = (N + 1023) / 1024;
  const int gN   = (N + 255) / 256;
  const int gEN  = (EN + 255) / 256;

  detect_kernel<<<1, 256, 0, stream>>>(eg32, E, flag);
  zero_int<<<gN, 256, 0, stream>>>(cnt, N);
  hist_kernel<<<gEN, 256, 0, stream>>>(eg64, eg32, flag, E, N, cnt);
  scan_blocks<<<nb, 1024, 0, stream>>>(cnt, rp, bsum, N);
  scan_sums<<<1, 64, 0, stream>>>(bsum, boff, nb);
  scan_add<<<nb, 1024, 0, stream>>>(rp, cursor, boff, N, EN);
  fill_kernel<<<gEN, 256, 0, stream>>>(eg64, eg32, flag, E, N, cursor, csr);

  // Layer 1
  gemm1_kernel<<<(N * 8 + 255) / 256, 256, 0, stream>>>(X, W1, h1, N);
  attn_kernel<2, 16><<<gN, 256, 0, stream>>>(h1, as1w, ad1w, as1, ad1, N);
  softmax_kernel<2><<<(N * 2 + 255) / 256, 256, 0, stream>>>(rp, csr, as1, ad1, al1, s1, N);
  agg_kernel<2, 16, true><<<(N * 8 + 255) / 256, 256, 0, stream>>>(rp, csr, al1, s1, h1, b1, x1, N);

  // Layer 2
  gemm2_kernel<<<(N * 10 + 255) / 256, 256, 0, stream>>>(x1, W2, h2, N);
  attn_kernel<1, 40><<<gN, 256, 0, stream>>>(h2, as2w, ad2w, as2, ad2, N);
  softmax_kernel<1><<<gN, 256, 0, stream>>>(rp, csr, as2, ad2, al2, s2, N);
  agg_kernel<1, 40, false><<<(N * 10 + 255) / 256, 256, 0, stream>>>(rp, csr, al2, s2, h2, b2, out, N);
}